// Round 1
// baseline (98.146 us; speedup 1.0000x reference)
//
#include <hip/hip_runtime.h>

// Chamfer loss: x,y (16, 4096, 3) fp32 -> scalar.
//
// Key algebra (matches the reference's own expansion):
//   d(x,y) = ||x||^2 + (||y||^2 - 2 x.y)
// ||x||^2 is constant per x-point, so the min over y only needs
//   t = ||y||^2 - 2 x.y  =  fma(-x0,2y0, fma(-x1,2y1, fma(-x2,2y2, ||y||^2)))
// i.e. 3 FMAs per pair (vs 7 VALU for the explicit difference form), with
// (2y0,2y1,2y2,||y||^2) precomputed once per y-point during LDS staging.
// Pairs of t merge with fminf(fminf(t0,t1),m) -> v_min3_f32: 3.5 VALU/pair.
//
// Pass 1: grid = 16 batches x 2 x-chunks(2048) x 16 y-chunks(256) = 512 blocks,
//   256 threads, 8 x-points/thread in registers, 256 y-points as float4 in LDS.
//   Partial min combined across y-chunk blocks with atomicMin on uint bits
//   (full distances clamped to >= 0, so float order == uint order).
// Pass 2: sum the 16*4096 mins, scale by 1/4096, atomicAdd into out.

constexpr int NPTS    = 4096;
constexpr int NBATCH  = 16;
constexpr int BLOCK   = 256;
constexpr int XPT     = 8;                   // x-points per thread
constexpr int XCHUNK  = BLOCK * XPT;         // 2048 x-points per block
constexpr int YTILE   = 256;                 // y-points per block (4 KB LDS)
constexpr int NXC     = NPTS / XCHUNK;       // 2
constexpr int NYC     = NPTS / YTILE;        // 16

__global__ __launch_bounds__(BLOCK) void chamfer_min_kernel(
    const float* __restrict__ x, const float* __restrict__ y,
    unsigned int* __restrict__ ws_min)
{
    __shared__ float4 sy[YTILE];             // (2y0, 2y1, 2y2, ||y||^2)

    const int b      = blockIdx.x >> 5;          // / (NXC*NYC) = /32
    const int xchunk = (blockIdx.x >> 4) & (NXC - 1);
    const int ychunk = blockIdx.x & (NYC - 1);

    // Stage this block's y tile: one point per thread (YTILE == BLOCK).
    {
        const float* yp = y + ((size_t)b * NPTS + ychunk * YTILE + threadIdx.x) * 3;
        const float y0 = yp[0], y1 = yp[1], y2 = yp[2];
        sy[threadIdx.x] = make_float4(
            2.0f * y0, 2.0f * y1, 2.0f * y2,
            fmaf(y2, y2, fmaf(y1, y1, y0 * y0)));
    }

    // Load this thread's 8 consecutive x-points (24 floats = 6 float4).
    const int xbase = xchunk * XCHUNK + threadIdx.x * XPT;
    const float4* xp4 = (const float4*)(x + ((size_t)b * NPTS + xbase) * 3);
    const float4 a0 = xp4[0], a1 = xp4[1], a2 = xp4[2];
    const float4 a3 = xp4[3], a4 = xp4[4], a5 = xp4[5];
    const float xa[XPT][3] = {
        {a0.x, a0.y, a0.z}, {a0.w, a1.x, a1.y},
        {a1.z, a1.w, a2.x}, {a2.y, a2.z, a2.w},
        {a3.x, a3.y, a3.z}, {a3.w, a4.x, a4.y},
        {a4.z, a4.w, a5.x}, {a5.y, a5.z, a5.w}};

    float x2s[XPT];
    #pragma unroll
    for (int i = 0; i < XPT; ++i)
        x2s[i] = fmaf(xa[i][2], xa[i][2],
                 fmaf(xa[i][1], xa[i][1], xa[i][0] * xa[i][0]));

    __syncthreads();

    float m[XPT];
    #pragma unroll
    for (int i = 0; i < XPT; ++i) m[i] = 3.4e38f;

    #pragma unroll 2
    for (int j = 0; j < YTILE; j += 2) {
        const float4 Y0 = sy[j];
        const float4 Y1 = sy[j + 1];
        #pragma unroll
        for (int i = 0; i < XPT; ++i) {
            const float t0 = fmaf(-xa[i][0], Y0.x,
                             fmaf(-xa[i][1], Y0.y,
                             fmaf(-xa[i][2], Y0.z, Y0.w)));
            const float t1 = fmaf(-xa[i][0], Y1.x,
                             fmaf(-xa[i][1], Y1.y,
                             fmaf(-xa[i][2], Y1.z, Y1.w)));
            m[i] = fminf(m[i], fminf(t0, t1));   // -> v_min3_f32
        }
    }

    // Full distance = ||x||^2 + min_t; clamp tiny negative rounding so the
    // uint-bits ordering trick remains valid, then combine across y-chunks.
    unsigned int* wm = ws_min + (size_t)b * NPTS + xbase;
    #pragma unroll
    for (int i = 0; i < XPT; ++i) {
        const float d = fmaxf(x2s[i] + m[i], 0.0f);
        atomicMin(&wm[i], __float_as_uint(d));
    }
}

__global__ __launch_bounds__(BLOCK) void chamfer_sum_kernel(
    const unsigned int* __restrict__ ws_min, float* __restrict__ out)
{
    __shared__ float swsum[BLOCK / 64];
    const int total = NBATCH * NPTS;
    float s = 0.f;
    for (int i = blockIdx.x * BLOCK + threadIdx.x; i < total;
         i += gridDim.x * BLOCK)
        s += __uint_as_float(ws_min[i]);

    for (int off = 32; off > 0; off >>= 1)
        s += __shfl_down(s, off, 64);
    const int wave = threadIdx.x >> 6;
    if ((threadIdx.x & 63) == 0) swsum[wave] = s;
    __syncthreads();
    if (threadIdx.x == 0) {
        float t = 0.f;
        #pragma unroll
        for (int w = 0; w < BLOCK / 64; ++w) t += swsum[w];
        atomicAdd(out, t * (1.0f / NPTS));
    }
}

extern "C" void kernel_launch(void* const* d_in, const int* in_sizes, int n_in,
                              void* d_out, int out_size, void* d_ws, size_t ws_size,
                              hipStream_t stream) {
    const float* x = (const float*)d_in[0];
    const float* y = (const float*)d_in[1];
    float* out = (float*)d_out;
    unsigned int* ws_min = (unsigned int*)d_ws;

    // ws: 16*4096 uints -> 0xFFFFFFFF (= +inf for uint-min of nonneg floats).
    hipMemsetAsync(ws_min, 0xFF, (size_t)NBATCH * NPTS * sizeof(unsigned int), stream);
    hipMemsetAsync(out, 0, sizeof(float), stream);

    const int grid1 = NBATCH * NXC * NYC;    // 512
    chamfer_min_kernel<<<grid1, BLOCK, 0, stream>>>(x, y, ws_min);
    chamfer_sum_kernel<<<64, BLOCK, 0, stream>>>(ws_min, out);
}

// Round 2
// 85.308 us; speedup vs baseline: 1.1505x; 1.1505x over previous
//
#include <hip/hip_runtime.h>

// Chamfer loss: x,y (16, 4096, 3) fp32 -> scalar.
//
// d(x,y) = ||x||^2 + (||y||^2 - 2 x.y); min over y only needs
//   t = fma(-x0,2y0, fma(-x1,2y1, fma(-x2,2y2, ||y||^2)))
// with (2y0,2y1,2y2,||y||^2) precomputed per y-point at LDS-staging time.
// 3 FMA + ~0.75 min per pair -> ~13 us VALU floor for 268M pairs.
//
// Round-2 changes (from rocprof):
//  - atomicMin combine wrote 32 MB through to HBM (1M atomics x 32B,
//    cross-XCD write-through) -> replaced with plain coalesced float4
//    stores of per-ychunk partials + a reduce kernel (min over NYC, sum).
//    No ws pre-memset needed.
//  - VGPR_Count was 32 (compiler squeezed ~40 live floats) -> launch_bounds
//    min-waves=4 caps VGPR at 128, giving scheduling/pipelining headroom.
//  - Occupancy 16% (512 blocks = 2 waves/SIMD) -> NYC=32 gives 1024 blocks
//    = 4 waves/SIMD.
//  - Host picks NYC by ws_size; falls back to the proven atomic path if
//    the workspace is smaller than 4 MB.

constexpr int NPTS   = 4096;
constexpr int NBATCH = 16;
constexpr int BLOCK  = 256;
constexpr int XPT    = 8;                    // x-points per thread
constexpr int XCHUNK = BLOCK * XPT;          // 2048 x-points per block
constexpr int NXC    = NPTS / XCHUNK;        // 2

// ---------------- pass 1: per-ychunk partial mins (store path) -------------

template <int NYC>
__global__ __launch_bounds__(BLOCK, 4) void chamfer_part_kernel(
    const float* __restrict__ x, const float* __restrict__ y,
    float* __restrict__ ws)
{
    constexpr int YTILE = NPTS / NYC;        // 128 (NYC=32) / 256 (NYC=16)
    __shared__ float4 sy[YTILE];             // (2y0, 2y1, 2y2, ||y||^2)

    const int b      = blockIdx.x / (NXC * NYC);
    const int xchunk = (blockIdx.x / NYC) % NXC;
    const int ychunk = blockIdx.x % NYC;

    for (int i = threadIdx.x; i < YTILE; i += BLOCK) {
        const float* yp = y + ((size_t)b * NPTS + ychunk * YTILE + i) * 3;
        const float y0 = yp[0], y1 = yp[1], y2 = yp[2];
        sy[i] = make_float4(2.0f * y0, 2.0f * y1, 2.0f * y2,
                            fmaf(y2, y2, fmaf(y1, y1, y0 * y0)));
    }

    // This thread's 8 consecutive x-points (24 floats = 6 float4).
    const int xbase = xchunk * XCHUNK + threadIdx.x * XPT;
    const float4* xp4 = (const float4*)(x + ((size_t)b * NPTS + xbase) * 3);
    const float4 a0 = xp4[0], a1 = xp4[1], a2 = xp4[2];
    const float4 a3 = xp4[3], a4 = xp4[4], a5 = xp4[5];
    const float xa[XPT][3] = {
        {a0.x, a0.y, a0.z}, {a0.w, a1.x, a1.y},
        {a1.z, a1.w, a2.x}, {a2.y, a2.z, a2.w},
        {a3.x, a3.y, a3.z}, {a3.w, a4.x, a4.y},
        {a4.z, a4.w, a5.x}, {a5.y, a5.z, a5.w}};

    float x2s[XPT];
    #pragma unroll
    for (int i = 0; i < XPT; ++i)
        x2s[i] = fmaf(xa[i][2], xa[i][2],
                 fmaf(xa[i][1], xa[i][1], xa[i][0] * xa[i][0]));

    __syncthreads();

    float m[XPT];
    #pragma unroll
    for (int i = 0; i < XPT; ++i) m[i] = 3.4e38f;

    #pragma unroll 2
    for (int j = 0; j < YTILE; j += 4) {
        const float4 Y0 = sy[j + 0];
        const float4 Y1 = sy[j + 1];
        const float4 Y2 = sy[j + 2];
        const float4 Y3 = sy[j + 3];
        #pragma unroll
        for (int i = 0; i < XPT; ++i) {
            const float t0 = fmaf(-xa[i][0], Y0.x,
                             fmaf(-xa[i][1], Y0.y,
                             fmaf(-xa[i][2], Y0.z, Y0.w)));
            const float t1 = fmaf(-xa[i][0], Y1.x,
                             fmaf(-xa[i][1], Y1.y,
                             fmaf(-xa[i][2], Y1.z, Y1.w)));
            const float t2 = fmaf(-xa[i][0], Y2.x,
                             fmaf(-xa[i][1], Y2.y,
                             fmaf(-xa[i][2], Y2.z, Y2.w)));
            const float t3 = fmaf(-xa[i][0], Y3.x,
                             fmaf(-xa[i][1], Y3.y,
                             fmaf(-xa[i][2], Y3.z, Y3.w)));
            m[i] = fminf(fminf(fminf(t0, t1), fminf(t2, t3)), m[i]);
        }
    }

    // Full distance (clamped at 0 like the passing round-1 kernel), stored
    // as plain floats: ws[b][ychunk][xpoint]. Coalesced 2x float4 per thread.
    float* wp = ws + ((size_t)b * NYC + ychunk) * NPTS + xbase;
    const float d0 = fmaxf(x2s[0] + m[0], 0.0f);
    const float d1 = fmaxf(x2s[1] + m[1], 0.0f);
    const float d2 = fmaxf(x2s[2] + m[2], 0.0f);
    const float d3 = fmaxf(x2s[3] + m[3], 0.0f);
    const float d4 = fmaxf(x2s[4] + m[4], 0.0f);
    const float d5 = fmaxf(x2s[5] + m[5], 0.0f);
    const float d6 = fmaxf(x2s[6] + m[6], 0.0f);
    const float d7 = fmaxf(x2s[7] + m[7], 0.0f);
    ((float4*)wp)[0] = make_float4(d0, d1, d2, d3);
    ((float4*)wp)[1] = make_float4(d4, d5, d6, d7);
}

// ---------------- pass 2: min over ychunks, then sum -----------------------

template <int NYC>
__global__ __launch_bounds__(BLOCK) void chamfer_reduce_kernel(
    const float* __restrict__ ws, float* __restrict__ out)
{
    __shared__ float swsum[BLOCK / 64];
    const int idx = blockIdx.x * BLOCK + threadIdx.x;   // one x-point each
    const int b   = idx / NPTS;
    const int xp  = idx % NPTS;

    float mn = 3.4e38f;
    #pragma unroll
    for (int yc = 0; yc < NYC; ++yc)
        mn = fminf(mn, ws[((size_t)b * NYC + yc) * NPTS + xp]);

    float s = mn;
    for (int off = 32; off > 0; off >>= 1)
        s += __shfl_down(s, off, 64);
    const int wave = threadIdx.x >> 6;
    if ((threadIdx.x & 63) == 0) swsum[wave] = s;
    __syncthreads();
    if (threadIdx.x == 0) {
        float t = 0.f;
        #pragma unroll
        for (int w = 0; w < BLOCK / 64; ++w) t += swsum[w];
        atomicAdd(out, t * (1.0f / NPTS));
    }
}

// ---------------- fallback: proven round-1 atomic path ---------------------

constexpr int FB_YTILE = 256;
constexpr int FB_NYC   = NPTS / FB_YTILE;    // 16

__global__ __launch_bounds__(BLOCK) void chamfer_min_atomic_kernel(
    const float* __restrict__ x, const float* __restrict__ y,
    unsigned int* __restrict__ ws_min)
{
    __shared__ float4 sy[FB_YTILE];

    const int b      = blockIdx.x / (NXC * FB_NYC);
    const int xchunk = (blockIdx.x / FB_NYC) % NXC;
    const int ychunk = blockIdx.x % FB_NYC;

    {
        const float* yp = y + ((size_t)b * NPTS + ychunk * FB_YTILE + threadIdx.x) * 3;
        const float y0 = yp[0], y1 = yp[1], y2 = yp[2];
        sy[threadIdx.x] = make_float4(2.0f * y0, 2.0f * y1, 2.0f * y2,
                                      fmaf(y2, y2, fmaf(y1, y1, y0 * y0)));
    }

    const int xbase = xchunk * XCHUNK + threadIdx.x * XPT;
    const float4* xp4 = (const float4*)(x + ((size_t)b * NPTS + xbase) * 3);
    const float4 a0 = xp4[0], a1 = xp4[1], a2 = xp4[2];
    const float4 a3 = xp4[3], a4 = xp4[4], a5 = xp4[5];
    const float xa[XPT][3] = {
        {a0.x, a0.y, a0.z}, {a0.w, a1.x, a1.y},
        {a1.z, a1.w, a2.x}, {a2.y, a2.z, a2.w},
        {a3.x, a3.y, a3.z}, {a3.w, a4.x, a4.y},
        {a4.z, a4.w, a5.x}, {a5.y, a5.z, a5.w}};

    float x2s[XPT];
    #pragma unroll
    for (int i = 0; i < XPT; ++i)
        x2s[i] = fmaf(xa[i][2], xa[i][2],
                 fmaf(xa[i][1], xa[i][1], xa[i][0] * xa[i][0]));

    __syncthreads();

    float m[XPT];
    #pragma unroll
    for (int i = 0; i < XPT; ++i) m[i] = 3.4e38f;

    #pragma unroll 2
    for (int j = 0; j < FB_YTILE; j += 2) {
        const float4 Y0 = sy[j];
        const float4 Y1 = sy[j + 1];
        #pragma unroll
        for (int i = 0; i < XPT; ++i) {
            const float t0 = fmaf(-xa[i][0], Y0.x,
                             fmaf(-xa[i][1], Y0.y,
                             fmaf(-xa[i][2], Y0.z, Y0.w)));
            const float t1 = fmaf(-xa[i][0], Y1.x,
                             fmaf(-xa[i][1], Y1.y,
                             fmaf(-xa[i][2], Y1.z, Y1.w)));
            m[i] = fminf(m[i], fminf(t0, t1));
        }
    }

    unsigned int* wm = ws_min + (size_t)b * NPTS + xbase;
    #pragma unroll
    for (int i = 0; i < XPT; ++i) {
        const float d = fmaxf(x2s[i] + m[i], 0.0f);
        atomicMin(&wm[i], __float_as_uint(d));
    }
}

__global__ __launch_bounds__(BLOCK) void chamfer_sum_kernel(
    const unsigned int* __restrict__ ws_min, float* __restrict__ out)
{
    __shared__ float swsum[BLOCK / 64];
    const int total = NBATCH * NPTS;
    float s = 0.f;
    for (int i = blockIdx.x * BLOCK + threadIdx.x; i < total;
         i += gridDim.x * BLOCK)
        s += __uint_as_float(ws_min[i]);

    for (int off = 32; off > 0; off >>= 1)
        s += __shfl_down(s, off, 64);
    const int wave = threadIdx.x >> 6;
    if ((threadIdx.x & 63) == 0) swsum[wave] = s;
    __syncthreads();
    if (threadIdx.x == 0) {
        float t = 0.f;
        #pragma unroll
        for (int w = 0; w < BLOCK / 64; ++w) t += swsum[w];
        atomicAdd(out, t * (1.0f / NPTS));
    }
}

// ---------------- host ------------------------------------------------------

extern "C" void kernel_launch(void* const* d_in, const int* in_sizes, int n_in,
                              void* d_out, int out_size, void* d_ws, size_t ws_size,
                              hipStream_t stream) {
    const float* x = (const float*)d_in[0];
    const float* y = (const float*)d_in[1];
    float* out = (float*)d_out;

    hipMemsetAsync(out, 0, sizeof(float), stream);

    const size_t need32 = (size_t)NBATCH * 32 * NPTS * sizeof(float);  // 8 MB
    const size_t need16 = (size_t)NBATCH * 16 * NPTS * sizeof(float);  // 4 MB

    if (ws_size >= need32) {
        float* ws = (float*)d_ws;
        chamfer_part_kernel<32><<<NBATCH * NXC * 32, BLOCK, 0, stream>>>(x, y, ws);
        chamfer_reduce_kernel<32><<<NBATCH * NPTS / BLOCK, BLOCK, 0, stream>>>(ws, out);
    } else if (ws_size >= need16) {
        float* ws = (float*)d_ws;
        chamfer_part_kernel<16><<<NBATCH * NXC * 16, BLOCK, 0, stream>>>(x, y, ws);
        chamfer_reduce_kernel<16><<<NBATCH * NPTS / BLOCK, BLOCK, 0, stream>>>(ws, out);
    } else {
        unsigned int* ws_min = (unsigned int*)d_ws;
        hipMemsetAsync(ws_min, 0xFF, (size_t)NBATCH * NPTS * sizeof(unsigned int),
                       stream);
        chamfer_min_atomic_kernel<<<NBATCH * NXC * FB_NYC, BLOCK, 0, stream>>>(
            x, y, ws_min);
        chamfer_sum_kernel<<<64, BLOCK, 0, stream>>>(ws_min, out);
    }
}